// Round 1
// baseline (3021.783 us; speedup 1.0000x reference)
//
#include <hip/hip_runtime.h>

#define NB 8
#define CC 256
#define LL 512
#define VV 25
#define PP 3

// ---------------------------------------------------------------------------
// Kernel A: causal 9-tap window sum along l.
//   xs[n,c,l,v] = sum_{j=max(0,l-8)}^{l} x[n,c,j,v]
// Written into d_out (used as scratch; fully overwritten by kernel B later).
// Thread handles one (n,c,v, l-chunk of 64); ring buffer of 8 (l0 % 8 == 0 so
// slot indices are static under the unrolled-by-8 inner loop -> stays in regs).
// ---------------------------------------------------------------------------
__global__ __launch_bounds__(256) void wsum_kernel(const float* __restrict__ x,
                                                   float* __restrict__ xs) {
    const int CHUNKS = 8;                       // 64 l's per chunk
    int t = blockIdx.x * 256 + threadIdx.x;
    if (t >= NB * CC * VV * CHUNKS) return;
    int v = t % VV;
    int r = t / VV;
    int chunk = r % CHUNKS;
    int nc = r / CHUNKS;                        // n*CC + c
    int l0 = chunk * (LL / CHUNKS);             // multiple of 8
    const float* xp = x  + (size_t)nc * (LL * VV) + v;
    float*       op = xs + (size_t)nc * (LL * VV) + v;

    float ring[8];
    float run = 0.f;                            // sum of x[l-8 .. l-1]
    #pragma unroll
    for (int k = 0; k < 8; ++k) {
        int j = l0 - 8 + k;
        float val = (j >= 0) ? xp[j * VV] : 0.f;
        ring[k] = val;                          // slot k == j % 8
        run += val;
    }
    for (int base = l0; base < l0 + LL / CHUNKS; base += 8) {
        #pragma unroll
        for (int k = 0; k < 8; ++k) {
            int l = base + k;                   // l % 8 == k
            float val = xp[l * VV];
            float o = run + val;                // sum x[l-8..l]
            op[l * VV] = o;
            run = o - ring[k];                  // drop x[l-8]
            ring[k] = val;
        }
    }
}

// ---------------------------------------------------------------------------
// Kernel B: fused conv(1x1, o=p*C+c) + A-mix + sum_p + BN + relu + residual.
// Block = one (n,l); 256 threads = 256 output channels c.
// In-place on d_out: reads xs[n,:,l,:] fully into LDS before writing
// out[n,:,l,:] (identical footprint -> no cross/intra-block hazard).
// NOTE: xs/out intentionally NOT __restrict__ (they alias).
// ---------------------------------------------------------------------------
__global__ __launch_bounds__(256) void fused_kernel(
    const float* xs,                    // aliases out
    const float* __restrict__ x,        // residual (original input)
    const float* __restrict__ W,        // (768, 256) row-major, row = p*256 + c
    const float* __restrict__ A,        // (3, 25, 25)
    const float* __restrict__ gamma,
    const float* __restrict__ beta,
    const float* __restrict__ mean,
    const float* __restrict__ var,
    float* out)
{
    __shared__ float xsh[CC][28];       // 28-pad: rows 112B (16B aligned) -> b128 reads
    const int bid = blockIdx.x;
    const int n = bid >> 9;             // / 512
    const int l = bid & 511;
    const int tid = threadIdx.x;
    const size_t nbase = (size_t)n * CC * LL * VV;

    // stage xs[n, :, l, :] (256 x 25) into LDS
    for (int k = tid; k < CC * VV; k += 256) {
        int ci = k / VV;
        int v  = k - ci * VV;
        xsh[ci][v] = xs[nbase + (size_t)ci * (LL * VV) + (size_t)l * VV + v];
    }
    __syncthreads();

    const int c = tid;
    float Y[PP * VV];
    #pragma unroll
    for (int i = 0; i < PP * VV; ++i) Y[i] = 0.f;

    const float* Wp = W + c * 256;      // row (p*256+c) at offset p*65536 + c*256

    #pragma unroll 1
    for (int ci = 0; ci < CC; ++ci) {
        float xv[VV];
        #pragma unroll
        for (int v = 0; v < VV; ++v) xv[v] = xsh[ci][v];
        float w0 = Wp[ci];
        float w1 = Wp[65536 + ci];
        float w2 = Wp[131072 + ci];
        #pragma unroll
        for (int v = 0; v < VV; ++v) Y[v]          = fmaf(w0, xv[v], Y[v]);
        #pragma unroll
        for (int v = 0; v < VV; ++v) Y[VV + v]     = fmaf(w1, xv[v], Y[VV + v]);
        #pragma unroll
        for (int v = 0; v < VV; ++v) Y[2 * VV + v] = fmaf(w2, xv[v], Y[2 * VV + v]);
    }

    // phase 2: o[w] = sum_{p,v} Y[p*25+v] * A[p,v,w]  (A reads are wave-uniform)
    float o[VV];
    #pragma unroll
    for (int w = 0; w < VV; ++w) o[w] = 0.f;
    #pragma unroll
    for (int p = 0; p < PP; ++p) {
        #pragma unroll
        for (int v = 0; v < VV; ++v) {
            float y = Y[p * VV + v];
            const float* Ap = A + (p * VV + v) * VV;
            #pragma unroll
            for (int w = 0; w < VV; ++w) o[w] = fmaf(y, Ap[w], o[w]);
        }
    }

    // BN + relu + residual-relu + store
    float sc = gamma[c] * rsqrtf(var[c] + 1e-5f);
    float sh = beta[c] - mean[c] * sc;
    const float* resp = x   + nbase + (size_t)c * (LL * VV) + (size_t)l * VV;
    float*       outp = out + nbase + (size_t)c * (LL * VV) + (size_t)l * VV;
    #pragma unroll
    for (int w = 0; w < VV; ++w) {
        float t2 = fmaf(o[w], sc, sh);
        t2 = fmaxf(t2, 0.f);
        t2 = fmaxf(t2 + resp[w], 0.f);
        outp[w] = t2;
    }
}

extern "C" void kernel_launch(void* const* d_in, const int* in_sizes, int n_in,
                              void* d_out, int out_size, void* d_ws, size_t ws_size,
                              hipStream_t stream) {
    const float* x  = (const float*)d_in[0];
    const float* W  = (const float*)d_in[1];
    const float* A  = (const float*)d_in[2];
    const float* gm = (const float*)d_in[3];
    const float* bt = (const float*)d_in[4];
    const float* mn = (const float*)d_in[5];
    const float* vr = (const float*)d_in[6];
    float* out = (float*)d_out;

    const int threadsA = NB * CC * VV * 8;      // 409600
    wsum_kernel<<<dim3((threadsA + 255) / 256), dim3(256), 0, stream>>>(x, out);
    fused_kernel<<<dim3(NB * LL), dim3(256), 0, stream>>>(out, x, W, A, gm, bt, mn, vr, out);
}

// Round 2
// 309.384 us; speedup vs baseline: 9.7671x; 9.7671x over previous
//
#include <hip/hip_runtime.h>
#include <hip/hip_bf16.h>

#define NB 8
#define CC 256
#define OO 768
#define LL 512
#define VV 25
#define PP 3

typedef __attribute__((ext_vector_type(8))) short short8v;
typedef __attribute__((ext_vector_type(4))) float float4v;

#define PITCH_XS 264   // bf16 elems per row, [32][264], 528B rows (16B aligned)
#define PITCH_Y2 104   // [256][104]
#define PITCH_A2 104   // [32][104]

// ---------------------------------------------------------------------------
// Kernel A: causal 9-tap window sum along l (validated round 1).
// ---------------------------------------------------------------------------
__global__ __launch_bounds__(256) void wsum_kernel(const float* __restrict__ x,
                                                   float* __restrict__ xs) {
    const int CHUNKS = 8;
    int t = blockIdx.x * 256 + threadIdx.x;
    if (t >= NB * CC * VV * CHUNKS) return;
    int v = t % VV;
    int r = t / VV;
    int chunk = r % CHUNKS;
    int nc = r / CHUNKS;
    int l0 = chunk * (LL / CHUNKS);
    const float* xp = x  + (size_t)nc * (LL * VV) + v;
    float*       op = xs + (size_t)nc * (LL * VV) + v;

    float ring[8];
    float run = 0.f;
    #pragma unroll
    for (int k = 0; k < 8; ++k) {
        int j = l0 - 8 + k;
        float val = (j >= 0) ? xp[j * VV] : 0.f;
        ring[k] = val;
        run += val;
    }
    for (int base = l0; base < l0 + LL / CHUNKS; base += 8) {
        #pragma unroll
        for (int k = 0; k < 8; ++k) {
            int l = base + k;
            float val = xp[l * VV];
            float o = run + val;
            op[l * VV] = o;
            run = o - ring[k];
            ring[k] = val;
        }
    }
}

// ---------------------------------------------------------------------------
// W fp32 -> bf16 copy into d_ws
// ---------------------------------------------------------------------------
__global__ __launch_bounds__(256) void wconv_kernel(const float* __restrict__ W,
                                                    __hip_bfloat16* __restrict__ Wb) {
    int i = blockIdx.x * 256 + threadIdx.x;
    if (i < OO * CC) Wb[i] = __float2bfloat16(W[i]);
}

// ---------------------------------------------------------------------------
// Kernel B: per-(n,l) block: GEMM1 Y=W*xs (MFMA), GEMM2 out=Y*A (MFMA),
// BN+relu+residual epilogue. In-place on d_out (xs aliases out).
// ---------------------------------------------------------------------------
template <bool USE_WB>
__global__ __launch_bounds__(256) void fused_mfma_kernel(
    const float* xs,                       // aliases out (NOT restrict)
    const float* __restrict__ x,           // residual
    const float* __restrict__ W,           // fp32 weights (fallback path)
    const __hip_bfloat16* __restrict__ Wb, // bf16 weights (if USE_WB)
    const float* __restrict__ A,           // (3,25,25)
    const float* __restrict__ gamma,
    const float* __restrict__ beta,
    const float* __restrict__ mean,
    const float* __restrict__ var,
    float* out)
{
    __shared__ __hip_bfloat16 xsT[32 * PITCH_XS];   // B-op GEMM1: [v][ci]
    __shared__ __hip_bfloat16 Y2[CC * PITCH_Y2];    // A-op GEMM2: [c][p*32+v]
    __shared__ __hip_bfloat16 A2T[32 * PITCH_A2];   // B-op GEMM2: [w][p*32+v]
    __shared__ float scsh[512];                     // sc[256], sh[256]

    const int bid = blockIdx.x;
    const int n = bid >> 9;
    const int l = bid & 511;
    const int tid = threadIdx.x;
    const size_t nbase = (size_t)n * CC * LL * VV;

    // ---- staging ----
    // xs tile -> xsT[v][ci] bf16
    #pragma unroll
    for (int it = 0; it < 25; ++it) {
        int idx = tid + it * 256;                 // idx < 6400
        int ci = idx / 25, v = idx - ci * 25;
        float f = xs[nbase + (size_t)ci * (LL * VV) + l * VV + v];
        xsT[v * PITCH_XS + ci] = __float2bfloat16(f);
    }
    // A -> A2T[w][p*32+v] (zeros outside valid range)
    for (int idx = tid; idx < 32 * PITCH_A2; idx += 256) {
        int w = idx / PITCH_A2, j = idx - w * PITCH_A2;
        int p = j >> 5, v = j & 31;
        float f = (w < 25 && v < 25 && j < 96) ? A[(p * 25 + v) * 25 + w] : 0.f;
        A2T[idx] = __float2bfloat16(f);
    }
    // zero all of Y2 (so K-pad and v-pad columns are 0)
    for (int idx = tid; idx < CC * PITCH_Y2 * 2 / 16; idx += 256) {
        float4v z = {0.f, 0.f, 0.f, 0.f};
        ((float4v*)Y2)[idx] = z;
    }
    // BN coefficients
    if (tid < 256) {
        float sc = gamma[tid] * rsqrtf(var[tid] + 1e-5f);
        scsh[tid] = sc;
        scsh[256 + tid] = beta[tid] - mean[tid] * sc;
    }
    __syncthreads();

    const int lane = tid & 63;
    const int wid = tid >> 6;
    const int lcol = lane & 15;
    const int lk = (lane >> 4) * 8;               // 0,8,16,24

    // ---- GEMM1: Y[768,25] = W[768,256] * xs[256,25] ----
    short8v bfr[2][8];
    #pragma unroll
    for (int nt = 0; nt < 2; ++nt)
        #pragma unroll
        for (int kk = 0; kk < 8; ++kk)
            bfr[nt][kk] = *(const short8v*)&xsT[(nt * 16 + lcol) * PITCH_XS + kk * 32 + lk];

    #pragma unroll 1
    for (int i = 0; i < 12; ++i) {
        int o0 = (wid * 12 + i) * 16;
        int orow = o0 + lcol;
        short8v afr[8];
        if (USE_WB) {
            #pragma unroll
            for (int kk = 0; kk < 8; ++kk)
                afr[kk] = *(const short8v*)&Wb[orow * 256 + kk * 32 + lk];
        } else {
            #pragma unroll
            for (int kk = 0; kk < 8; ++kk) {
                float4v w0 = *(const float4v*)&W[orow * 256 + kk * 32 + lk];
                float4v w1 = *(const float4v*)&W[orow * 256 + kk * 32 + lk + 4];
                short8v a;
                #pragma unroll
                for (int j = 0; j < 4; ++j) {
                    __hip_bfloat16 h0 = __float2bfloat16(w0[j]);
                    __hip_bfloat16 h1 = __float2bfloat16(w1[j]);
                    a[j]     = *reinterpret_cast<short*>(&h0);
                    a[j + 4] = *reinterpret_cast<short*>(&h1);
                }
                afr[kk] = a;
            }
        }
        #pragma unroll
        for (int nt = 0; nt < 2; ++nt) {
            float4v acc = {0.f, 0.f, 0.f, 0.f};
            #pragma unroll
            for (int kk = 0; kk < 8; ++kk)
                acc = __builtin_amdgcn_mfma_f32_16x16x32_bf16(afr[kk], bfr[nt][kk], acc, 0, 0, 0);
            int v = nt * 16 + lcol;
            if (v < 25) {
                int rbase = (lane >> 4) * 4;
                #pragma unroll
                for (int r = 0; r < 4; ++r) {
                    int o = o0 + rbase + r;           // o = p*256 + c
                    Y2[(o & 255) * PITCH_Y2 + (o >> 8) * 32 + v] = __float2bfloat16(acc[r]);
                }
            }
        }
    }
    __syncthreads();

    // ---- GEMM2: out[256,25] = Y2[256,96] * A2[96,25] + BN/relu/res ----
    short8v bf2[2][3];
    #pragma unroll
    for (int nt = 0; nt < 2; ++nt)
        #pragma unroll
        for (int kk = 0; kk < 3; ++kk)
            bf2[nt][kk] = *(const short8v*)&A2T[(nt * 16 + lcol) * PITCH_A2 + kk * 32 + lk];

    #pragma unroll
    for (int i = 0; i < 4; ++i) {
        int c0 = (wid * 4 + i) * 16;
        int crow = c0 + lcol;
        short8v af2[3];
        #pragma unroll
        for (int kk = 0; kk < 3; ++kk)
            af2[kk] = *(const short8v*)&Y2[crow * PITCH_Y2 + kk * 32 + lk];
        #pragma unroll
        for (int nt = 0; nt < 2; ++nt) {
            float4v acc = {0.f, 0.f, 0.f, 0.f};
            #pragma unroll
            for (int kk = 0; kk < 3; ++kk)
                acc = __builtin_amdgcn_mfma_f32_16x16x32_bf16(af2[kk], bf2[nt][kk], acc, 0, 0, 0);
            int w = nt * 16 + lcol;
            if (w < 25) {
                #pragma unroll
                for (int r = 0; r < 4; ++r) {
                    int c = c0 + (lane >> 4) * 4 + r;
                    float val = fmaf(acc[r], scsh[c], scsh[256 + c]);
                    val = fmaxf(val, 0.f);
                    size_t oaddr = nbase + (size_t)c * (LL * VV) + l * VV + w;
                    val = fmaxf(val + x[oaddr], 0.f);
                    out[oaddr] = val;
                }
            }
        }
    }
}

extern "C" void kernel_launch(void* const* d_in, const int* in_sizes, int n_in,
                              void* d_out, int out_size, void* d_ws, size_t ws_size,
                              hipStream_t stream) {
    const float* x  = (const float*)d_in[0];
    const float* W  = (const float*)d_in[1];
    const float* A  = (const float*)d_in[2];
    const float* gm = (const float*)d_in[3];
    const float* bt = (const float*)d_in[4];
    const float* mn = (const float*)d_in[5];
    const float* vr = (const float*)d_in[6];
    float* out = (float*)d_out;

    const int threadsA = NB * CC * VV * 8;
    wsum_kernel<<<dim3((threadsA + 255) / 256), dim3(256), 0, stream>>>(x, out);

    bool useWb = ws_size >= (size_t)(OO * CC * sizeof(__hip_bfloat16));
    __hip_bfloat16* Wb = (__hip_bfloat16*)d_ws;
    if (useWb) {
        wconv_kernel<<<dim3((OO * CC + 255) / 256), dim3(256), 0, stream>>>(W, Wb);
        fused_mfma_kernel<true><<<dim3(NB * LL), dim3(256), 0, stream>>>(
            out, x, W, Wb, A, gm, bt, mn, vr, out);
    } else {
        fused_mfma_kernel<false><<<dim3(NB * LL), dim3(256), 0, stream>>>(
            out, x, W, Wb, A, gm, bt, mn, vr, out);
    }
}